// Round 1
// baseline (172.682 us; speedup 1.0000x reference)
//
#include <hip/hip_runtime.h>
#include <math.h>

static constexpr float kNegSlope = 0.2f;
static constexpr float kEps = 1e-16f;
static constexpr int SLICES = 256;   // partition slices for hist/bin passes
static constexpr int BSHIFT = 7;     // 128 nodes per bucket
static constexpr int BMASK = 127;
static constexpr unsigned SRCMASK = 0x1FFFFu;  // 17 bits (N < 131072)
static constexpr int CAP = 2816;     // LDS bucket capacity (mean 2048, +17 sigma)

__device__ __forceinline__ float leaky(float v) {
    return v > 0.0f ? v : kNegSlope * v;
}

// ================= atomic-free bucketed partition =================
// bucket = dst >> 7 (128 nodes). Per-slice private LDS histograms ->
// scan of table[bucket][slice] -> deterministic scatter with LDS cursors.
// Record: src | (d&127)<<17 (24 bits). 4B records ONLY — R16 showed widening
// the scattered record (8B) doubles write amplification. No global atomics.

__global__ __launch_bounds__(512) void k_hist1(const int* __restrict__ ei,
                                               int* __restrict__ table,
                                               int* __restrict__ rowptr,
                                               int E, int N, int NBUCK) {
    __shared__ int hist[832];
    int b = blockIdx.x, t = threadIdx.x;
    if (b == 0 && t == 0) rowptr[N] = E;  // sentinel
    for (int i = t; i < NBUCK; i += 512) hist[i] = 0;
    __syncthreads();
    int S = (((E + SLICES - 1) / SLICES) + 3) & ~3;  // slice size, multiple of 4
    int lo = b * S, hi = min(lo + S, E);
    for (int i = lo + t * 4; i < hi; i += 512 * 4) {
        int4 dv = *(const int4*)(ei + E + i);
        atomicAdd(&hist[dv.x >> BSHIFT], 1);
        atomicAdd(&hist[dv.y >> BSHIFT], 1);
        atomicAdd(&hist[dv.z >> BSHIFT], 1);
        atomicAdd(&hist[dv.w >> BSHIFT], 1);
    }
    __syncthreads();
    for (int i = t; i < NBUCK; i += 512) table[i * SLICES + b] = hist[i];
}

// Scan pass 1: block b sums its 1024-int chunk -> partial[b].
__global__ __launch_bounds__(256) void k_scan_reduce(const int* __restrict__ src,
                                                     int* __restrict__ partial, int n) {
    __shared__ int wsum[4];
    int b = blockIdx.x, t = threadIdx.x;
    int base = b * 1024 + t * 4;
    int s = 0;
#pragma unroll
    for (int k = 0; k < 4; ++k) {
        int idx = base + k;
        s += (idx < n) ? src[idx] : 0;
    }
#pragma unroll
    for (int off = 1; off < 64; off <<= 1) s += __shfl_xor(s, off);
    if ((t & 63) == 0) wsum[t >> 6] = s;
    __syncthreads();
    if (t == 0) partial[b] = wsum[0] + wsum[1] + wsum[2] + wsum[3];
}

// Scan pass 2: block b computes its chunk base by reducing partial[i<b],
// then wave-scans its 1024-int chunk in place (exclusive).
__global__ __launch_bounds__(256) void k_scan_apply(int* __restrict__ data,
                                                    const int* __restrict__ partial,
                                                    int n, int nsb) {
    __shared__ int sm[8];
    __shared__ int baseSh;
    int b = blockIdx.x, t = threadIdx.x;
    int acc = 0;
    for (int i = t; i < b; i += 256) acc += partial[i];
#pragma unroll
    for (int off = 1; off < 64; off <<= 1) acc += __shfl_xor(acc, off);
    if ((t & 63) == 0) sm[t >> 6] = acc;
    __syncthreads();
    if (t == 0) baseSh = sm[0] + sm[1] + sm[2] + sm[3];
    __syncthreads();
    int chunkBase = baseSh;
    __syncthreads();  // sm reused below
    int base = b * 1024 + t * 4;
    int v[4];
#pragma unroll
    for (int k = 0; k < 4; ++k) {
        int idx = base + k;
        v[k] = (idx < n) ? data[idx] : 0;
    }
    int sum4 = v[0] + v[1] + v[2] + v[3];
    int s = sum4;
#pragma unroll
    for (int off = 1; off < 64; off <<= 1) {
        int u = __shfl_up(s, off);
        if ((t & 63) >= off) s += u;
    }
    if ((t & 63) == 63) sm[t >> 6] = s;
    __syncthreads();
    int woff = 0;
    int w = t >> 6;
    for (int ww = 0; ww < w; ++ww) woff += sm[ww];
    int ex = chunkBase + woff + (s - sum4);
#pragma unroll
    for (int k = 0; k < 4; ++k) {
        int idx = base + k;
        if (idx < n) data[idx] = ex;
        ex += v[k];
    }
}

__global__ __launch_bounds__(512) void k_bin2(const int* __restrict__ ei,
                                              const int* __restrict__ table,
                                              unsigned* __restrict__ sbuf, int E, int NBUCK) {
    __shared__ int cur[832];
    int b = blockIdx.x, t = threadIdx.x;
    for (int i = t; i < NBUCK; i += 512) cur[i] = table[i * SLICES + b];
    __syncthreads();
    int S = (((E + SLICES - 1) / SLICES) + 3) & ~3;
    int lo = b * S, hi = min(lo + S, E);
    for (int i = lo + t * 4; i < hi; i += 512 * 4) {
        int4 sv = *(const int4*)(ei + i);
        int4 dv = *(const int4*)(ei + E + i);
        int pos;
        pos = atomicAdd(&cur[dv.x >> BSHIFT], 1);
        sbuf[pos] = (unsigned)sv.x | ((unsigned)(dv.x & BMASK) << 17);
        pos = atomicAdd(&cur[dv.y >> BSHIFT], 1);
        sbuf[pos] = (unsigned)sv.y | ((unsigned)(dv.y & BMASK) << 17);
        pos = atomicAdd(&cur[dv.z >> BSHIFT], 1);
        sbuf[pos] = (unsigned)sv.z | ((unsigned)(dv.z & BMASK) << 17);
        pos = atomicAdd(&cur[dv.w >> BSHIFT], 1);
        sbuf[pos] = (unsigned)sv.w | ((unsigned)(dv.w & BMASK) << 17);
    }
}

// ================= per-bucket counting sort -> CSR =================
// One 512-thread block per 128-node bucket: stage records into LDS, hist,
// two-wave shfl scan -> rowptr, LDS->LDS counting sort, COALESCED ssrc
// writeback. No gather work here — R18 showed fusing the gather into this
// block serializes it behind the sort phases. Keep blocks short.
__global__ __launch_bounds__(512) void k_sort(
        const unsigned* __restrict__ sbuf, const int* __restrict__ table,
        int* __restrict__ rowptr, int* __restrict__ ssrc,
        int N, int E, int NBUCK) {
    __shared__ int hist[128];
    __shared__ int sc[128];
    __shared__ int cur[128];
    __shared__ unsigned raws[CAP];
    __shared__ int sls[CAP];
    int b = blockIdx.x;
    int t = threadIdx.x;
    int lo = table[b * SLICES];
    int hi = (b + 1 < NBUCK) ? table[(b + 1) * SLICES] : E;
    int cnt = hi - lo;
    bool inLds = (cnt <= CAP);

    if (t < 128) hist[t] = 0;
    __syncthreads();

    if (inLds) {
        for (int i = t; i < cnt; i += 512) {
            unsigned v = sbuf[lo + i];
            raws[i] = v;
            atomicAdd(&hist[v >> 17], 1);
        }
    } else {
        for (int i = lo + t; i < hi; i += 512) atomicAdd(&hist[sbuf[i] >> 17], 1);
    }
    __syncthreads();

    if (t < 128) {  // two-wave shfl inclusive scan of 128 bins
        int lane = t & 63;
        int own = hist[t];
        int v = own;
#pragma unroll
        for (int off = 1; off < 64; off <<= 1) {
            int u = __shfl_up(v, off);
            if (lane >= off) v += u;
        }
        sc[t] = v;
    }
    __syncthreads();
    if (t < 128) {
        int ex = sc[t] - hist[t] + (t >= 64 ? sc[63] : 0);
        cur[t] = ex;
        int node = (b << BSHIFT) + t;
        if (node < N) rowptr[node] = lo + ex;
    }
    __syncthreads();

    if (inLds) {
        for (int i = t; i < cnt; i += 512) {
            unsigned v = raws[i];
            int pos = atomicAdd(&cur[v >> 17], 1);
            sls[pos] = (int)(v & SRCMASK);
        }
        __syncthreads();
        for (int i = t; i < cnt; i += 512) ssrc[lo + i] = sls[i];  // coalesced
    } else {  // overflow fallback (statistically never: mean 2048, CAP 2816)
        for (int i = lo + t; i < hi; i += 512) {
            unsigned v = sbuf[i];
            int pos = atomicAdd(&cur[v >> 17], 1);
            ssrc[lo + pos] = (int)(v & SRCMASK);
        }
    }
}

// ================= edge-order feature materialization =================
// sxy[e] = x[ssrc[e]] (float2). Breaks the ssrc->x dependent-gather chain out
// of k_gather1's latency-critical loop: here the 4 gathers/thread are fully
// independent and hidden by massive TLP; the write is coalesced. k_gather1
// then STREAMS sxy with zero indirection. (R0-polish: gather1 was 48us at
// 22% VALU / 2.3% HBM = latency-bound on the 2-deep ssrc->x chain.)
__global__ __launch_bounds__(256) void k_fill(const int* __restrict__ ssrc,
                                              const float* __restrict__ x,
                                              float* __restrict__ sxy, int E) {
    int i4 = (blockIdx.x * 256 + threadIdx.x) * 4;
    const float2* x2 = (const float2*)x;
    if (i4 + 3 < E) {
        int4 s = *(const int4*)(ssrc + i4);
        float2 a = x2[s.x];
        float2 b = x2[s.y];
        float2 c = x2[s.z];
        float2 d = x2[s.w];
        *(float4*)(sxy + 2 * i4)     = make_float4(a.x, a.y, b.x, b.y);
        *(float4*)(sxy + 2 * i4 + 4) = make_float4(c.x, c.y, d.x, d.y);
    } else {
        for (int i = i4; i < E; ++i) {
            float2 a = x2[ssrc[i]];
            sxy[2 * i] = a.x;
            sxy[2 * i + 1] = a.y;
        }
    }
}

// ================= layer 1 gather + transform 2 (node-parallel) =================
// 8 lanes/node (800k threads). Inner loop now streams sxy (coalesced float2,
// no indirection). Straight-line segment-sum softmax on rank-2 features (no
// max: inputs N(0,1)-scale, |e|<~8 — validated R8-R18); epilogue folds
// W1->relu->W2.
__global__ __launch_bounds__(256) void k_gather1(
        const int* __restrict__ rowptr, const float* __restrict__ sxy,
        const float* __restrict__ x,
        const float* __restrict__ W1, const float* __restrict__ att_src1,
        const float* __restrict__ att_dst1, const float* __restrict__ b1,
        const float* __restrict__ W2, float* __restrict__ h2, int N) {
    __shared__ float pbuf[32];  // Ps d0 | Ps d1 | Pd d0 | Pd d1 (8 heads each)
    int t = threadIdx.x;
    if (t < 32) {  // rank-2 projections
        int which = t >> 4;   // 0=src, 1=dst
        int hd = t & 15;
        int h = hd >> 1, d = hd & 1;
        const float* att = which ? att_dst1 : att_src1;
        float s = 0.0f;
#pragma unroll
        for (int c = 0; c < 16; ++c) s += W1[d * 128 + h * 16 + c] * att[h * 16 + c];
        pbuf[which * 16 + d * 8 + h] = s;
    }
    __syncthreads();

    int idx = blockIdx.x * blockDim.x + t;
    int n = idx >> 3, q = idx & 7;
    if (n >= N) return;
    const float2* x2 = (const float2*)x;
    const float2* sx2 = (const float2*)sxy;
    int start = rowptr[n], end = rowptr[n + 1];
    float2 xn = x2[n];
    float Ps0[8], Ps1[8], adv[8], l[8], s0[8], s1[8];
#pragma unroll
    for (int h = 0; h < 8; ++h) {
        Ps0[h] = pbuf[h];
        Ps1[h] = pbuf[8 + h];
        adv[h] = xn.x * pbuf[16 + h] + xn.y * pbuf[24 + h];
        l[h] = 0.f; s0[h] = 0.f; s1[h] = 0.f;
    }
    for (int j = start + q; j < end; j += 8) {
        float2 xs = sx2[j];  // streaming, coalesced — no gather chain
#pragma unroll
        for (int h = 0; h < 8; ++h) {
            float p = __expf(leaky(xs.x * Ps0[h] + xs.y * Ps1[h] + adv[h]));
            l[h] += p; s0[h] += p * xs.x; s1[h] += p * xs.y;
        }
    }
#pragma unroll
    for (int off = 1; off < 8; off <<= 1) {
#pragma unroll
        for (int h = 0; h < 8; ++h) {
            l[h] += __shfl_xor(l[h], off);
            s0[h] += __shfl_xor(s0[h], off);
            s1[h] += __shfl_xor(s1[h], off);
        }
    }
    // lane q folds head q through W1->relu->W2
    float h0 = 0.f, h1v = 0.f, h2v = 0.f, h3 = 0.f;
    {
        float inv = 1.0f / (l[q] + kEps);
        float sX0 = s0[q] * inv, sX1 = s1[q] * inv;
#pragma unroll
        for (int c = 0; c < 16; ++c) {
            int col = q * 16 + c;
            float o = fmaxf(W1[col] * sX0 + W1[128 + col] * sX1 + b1[col], 0.0f);
            h0 += o * W2[col * 4 + 0];
            h1v += o * W2[col * 4 + 1];
            h2v += o * W2[col * 4 + 2];
            h3 += o * W2[col * 4 + 3];
        }
    }
#pragma unroll
    for (int off = 1; off < 8; off <<= 1) {
        h0 += __shfl_xor(h0, off);
        h1v += __shfl_xor(h1v, off);
        h2v += __shfl_xor(h2v, off);
        h3 += __shfl_xor(h3, off);
    }
    if (q == 0) {
        ((float4*)h2)[n] = make_float4(h0, h1v, h2v, h3);
    }
}

// ================= layer 2 gather + log_softmax =================
// 8 lanes/node; attention dots recomputed from h2. h2[src] gather can't be
// de-indirected (h2 is produced between the layers), so unroll-by-2 keeps
// two independent ssrc->h2 chains in flight per iteration (2x MLP).
__global__ __launch_bounds__(256) void k_gather2_out(
        const int* __restrict__ rowptr, const int* __restrict__ ssrc,
        const float* __restrict__ h2, const float* __restrict__ att_src2,
        const float* __restrict__ att_dst2, const float* __restrict__ b2,
        float* __restrict__ out, int N) {
    int idx = blockIdx.x * blockDim.x + threadIdx.x;
    int n = idx >> 3, q = idx & 7;
    if (n >= N) return;
    int start = rowptr[n], end = rowptr[n + 1];
    float4 as2 = *(const float4*)att_src2;
    float4 ad2v = *(const float4*)att_dst2;
    const float4* h4 = (const float4*)h2;
    float4 hn = h4[n];
    float ad = hn.x * ad2v.x + hn.y * ad2v.y + hn.z * ad2v.z + hn.w * ad2v.w;
    float l = 0.0f;
    float4 acc = make_float4(0.f, 0.f, 0.f, 0.f);
    int j = start + q;
    for (; j + 8 < end; j += 16) {  // two independent gathers in flight
        int s0 = ssrc[j];
        int s1 = ssrc[j + 8];
        float4 ha = h4[s0];
        float4 hb = h4[s1];
        float e0 = ha.x * as2.x + ha.y * as2.y + ha.z * as2.z + ha.w * as2.w + ad;
        float e1 = hb.x * as2.x + hb.y * as2.y + hb.z * as2.z + hb.w * as2.w + ad;
        float p0 = __expf(leaky(e0));
        float p1 = __expf(leaky(e1));
        l += p0 + p1;
        acc.x += p0 * ha.x + p1 * hb.x;
        acc.y += p0 * ha.y + p1 * hb.y;
        acc.z += p0 * ha.z + p1 * hb.z;
        acc.w += p0 * ha.w + p1 * hb.w;
    }
    if (j < end) {  // at most one tail edge per lane
        int s0 = ssrc[j];
        float4 ha = h4[s0];
        float e0 = ha.x * as2.x + ha.y * as2.y + ha.z * as2.z + ha.w * as2.w + ad;
        float p0 = __expf(leaky(e0));
        l += p0;
        acc.x += p0 * ha.x;
        acc.y += p0 * ha.y;
        acc.z += p0 * ha.z;
        acc.w += p0 * ha.w;
    }
#pragma unroll
    for (int off = 1; off < 8; off <<= 1) {
        l += __shfl_xor(l, off);
        acc.x += __shfl_xor(acc.x, off);
        acc.y += __shfl_xor(acc.y, off);
        acc.z += __shfl_xor(acc.z, off);
        acc.w += __shfl_xor(acc.w, off);
    }
    if (q == 0) {
        float inv = 1.0f / (l + kEps);
        float4 v = make_float4(acc.x * inv + b2[0], acc.y * inv + b2[1],
                               acc.z * inv + b2[2], acc.w * inv + b2[3]);
        float mx = fmaxf(fmaxf(v.x, v.y), fmaxf(v.z, v.w));
        float sum = __expf(v.x - mx) + __expf(v.y - mx) + __expf(v.z - mx) + __expf(v.w - mx);
        float lse = mx + logf(sum);
        ((float4*)out)[n] = make_float4(v.x - lse, v.y - lse, v.z - lse, v.w - lse);
    }
}

extern "C" void kernel_launch(void* const* d_in, const int* in_sizes, int n_in,
                              void* d_out, int out_size, void* d_ws, size_t ws_size,
                              hipStream_t stream) {
    const float* x        = (const float*)d_in[0];
    const int*   ei       = (const int*)d_in[1];
    const float* W1       = (const float*)d_in[2];
    const float* att_src1 = (const float*)d_in[3];
    const float* att_dst1 = (const float*)d_in[4];
    const float* b1       = (const float*)d_in[5];
    const float* W2       = (const float*)d_in[6];
    const float* att_src2 = (const float*)d_in[7];
    const float* att_dst2 = (const float*)d_in[8];
    const float* b2       = (const float*)d_in[9];

    const int N = in_sizes[0] / 2;           // x is [N,2]
    const int E = in_sizes[1] / 2;           // edge_index is [2,E]
    const int NBUCK = (N + BMASK) >> BSHIFT; // 128-node buckets (<= 832)
    const int ntable = NBUCK * SLICES;
    const int nsb = (ntable + 1023) / 1024;  // scan chunks
    const int Epad = (E + 3) & ~3;

    // ---- workspace layout (4B elems) ----
    // sxy (2E floats) OVERLAYS sbuf (dead after k_sort) + E more ints:
    // net growth vs prior layout is just +E ints.
    int* table     = (int*)d_ws;                  // ntable (+64 pad)
    int* partial   = table + ntable + 64;         // nsb (pad 1024)
    int* rowptr    = partial + 1024;              // N+1 -> pad N+4
    int* ssrc      = rowptr + ((N + 4) & ~3);     // Epad
    unsigned* sbuf = (unsigned*)(ssrc + Epad);    // Epad (dead after k_sort)
    float* sxy     = (float*)sbuf;                // 2*Epad floats (overlays sbuf)
    float* h2      = (float*)((int*)sbuf + 2 * (size_t)Epad);  // N*4

    // bucketed partition (by destination), no global atomics
    k_hist1<<<SLICES, 512, 0, stream>>>(ei, table, rowptr, E, N, NBUCK);
    k_scan_reduce<<<nsb, 256, 0, stream>>>(table, partial, ntable);
    k_scan_apply<<<nsb, 256, 0, stream>>>(table, partial, ntable, nsb);
    k_bin2<<<SLICES, 512, 0, stream>>>(ei, table, sbuf, E, NBUCK);

    // per-bucket counting sort -> CSR
    k_sort<<<NBUCK, 512, 0, stream>>>(sbuf, table, rowptr, ssrc, N, E, NBUCK);

    // edge-order x materialization (kills gather1's dependent-gather chain)
    k_fill<<<((E + 3) / 4 + 255) / 256, 256, 0, stream>>>(ssrc, x, sxy, E);

    // layer 1 gather + transform 2 (node-parallel, streaming sxy)
    k_gather1<<<(N * 8 + 255) / 256, 256, 0, stream>>>(rowptr, sxy, x,
                                                       W1, att_src1, att_dst1, b1,
                                                       W2, h2, N);

    // layer 2 gather + log_softmax
    k_gather2_out<<<(N * 8 + 255) / 256, 256, 0, stream>>>(rowptr, ssrc, h2,
                                                           att_src2, att_dst2, b2,
                                                           (float*)d_out, N);
}

// Round 2
// 168.802 us; speedup vs baseline: 1.0230x; 1.0230x over previous
//
#include <hip/hip_runtime.h>
#include <math.h>

static constexpr float kNegSlope = 0.2f;
static constexpr float kEps = 1e-16f;
static constexpr int SLICES = 256;   // partition slices for hist/bin passes
static constexpr int BSHIFT = 7;     // 128 nodes per bucket
static constexpr int BMASK = 127;
static constexpr unsigned SRCMASK = 0x1FFFFu;  // 17 bits (N < 131072)
static constexpr int CAP = 2816;     // LDS bucket capacity (mean 2048, +17 sigma)

__device__ __forceinline__ float leaky(float v) {
    return v > 0.0f ? v : kNegSlope * v;
}

// ================= atomic-free bucketed partition =================
// bucket = dst >> 7 (128 nodes). Per-slice private LDS histograms ->
// scan of table[bucket][slice] -> deterministic scatter with LDS cursors.
// Record: src | (d&127)<<17 (24 bits). 4B records ONLY — R16 showed widening
// the scattered record (8B) doubles write amplification. No global atomics.

__global__ __launch_bounds__(512) void k_hist1(const int* __restrict__ ei,
                                               int* __restrict__ table,
                                               int* __restrict__ rowptr,
                                               int E, int N, int NBUCK) {
    __shared__ int hist[832];
    int b = blockIdx.x, t = threadIdx.x;
    if (b == 0 && t == 0) rowptr[N] = E;  // sentinel
    for (int i = t; i < NBUCK; i += 512) hist[i] = 0;
    __syncthreads();
    int S = (((E + SLICES - 1) / SLICES) + 3) & ~3;  // slice size, multiple of 4
    int lo = b * S, hi = min(lo + S, E);
    for (int i = lo + t * 4; i < hi; i += 512 * 4) {
        int4 dv = *(const int4*)(ei + E + i);
        atomicAdd(&hist[dv.x >> BSHIFT], 1);
        atomicAdd(&hist[dv.y >> BSHIFT], 1);
        atomicAdd(&hist[dv.z >> BSHIFT], 1);
        atomicAdd(&hist[dv.w >> BSHIFT], 1);
    }
    __syncthreads();
    for (int i = t; i < NBUCK; i += 512) table[i * SLICES + b] = hist[i];
}

// Scan pass 1: block b sums its 1024-int chunk -> partial[b].
__global__ __launch_bounds__(256) void k_scan_reduce(const int* __restrict__ src,
                                                     int* __restrict__ partial, int n) {
    __shared__ int wsum[4];
    int b = blockIdx.x, t = threadIdx.x;
    int base = b * 1024 + t * 4;
    int s = 0;
#pragma unroll
    for (int k = 0; k < 4; ++k) {
        int idx = base + k;
        s += (idx < n) ? src[idx] : 0;
    }
#pragma unroll
    for (int off = 1; off < 64; off <<= 1) s += __shfl_xor(s, off);
    if ((t & 63) == 0) wsum[t >> 6] = s;
    __syncthreads();
    if (t == 0) partial[b] = wsum[0] + wsum[1] + wsum[2] + wsum[3];
}

// Scan pass 2: block b computes its chunk base by reducing partial[i<b],
// then wave-scans its 1024-int chunk in place (exclusive).
__global__ __launch_bounds__(256) void k_scan_apply(int* __restrict__ data,
                                                    const int* __restrict__ partial,
                                                    int n, int nsb) {
    __shared__ int sm[8];
    __shared__ int baseSh;
    int b = blockIdx.x, t = threadIdx.x;
    int acc = 0;
    for (int i = t; i < b; i += 256) acc += partial[i];
#pragma unroll
    for (int off = 1; off < 64; off <<= 1) acc += __shfl_xor(acc, off);
    if ((t & 63) == 0) sm[t >> 6] = acc;
    __syncthreads();
    if (t == 0) baseSh = sm[0] + sm[1] + sm[2] + sm[3];
    __syncthreads();
    int chunkBase = baseSh;
    __syncthreads();  // sm reused below
    int base = b * 1024 + t * 4;
    int v[4];
#pragma unroll
    for (int k = 0; k < 4; ++k) {
        int idx = base + k;
        v[k] = (idx < n) ? data[idx] : 0;
    }
    int sum4 = v[0] + v[1] + v[2] + v[3];
    int s = sum4;
#pragma unroll
    for (int off = 1; off < 64; off <<= 1) {
        int u = __shfl_up(s, off);
        if ((t & 63) >= off) s += u;
    }
    if ((t & 63) == 63) sm[t >> 6] = s;
    __syncthreads();
    int woff = 0;
    int w = t >> 6;
    for (int ww = 0; ww < w; ++ww) woff += sm[ww];
    int ex = chunkBase + woff + (s - sum4);
#pragma unroll
    for (int k = 0; k < 4; ++k) {
        int idx = base + k;
        if (idx < n) data[idx] = ex;
        ex += v[k];
    }
}

__global__ __launch_bounds__(512) void k_bin2(const int* __restrict__ ei,
                                              const int* __restrict__ table,
                                              unsigned* __restrict__ sbuf, int E, int NBUCK) {
    __shared__ int cur[832];
    int b = blockIdx.x, t = threadIdx.x;
    for (int i = t; i < NBUCK; i += 512) cur[i] = table[i * SLICES + b];
    __syncthreads();
    int S = (((E + SLICES - 1) / SLICES) + 3) & ~3;
    int lo = b * S, hi = min(lo + S, E);
    for (int i = lo + t * 4; i < hi; i += 512 * 4) {
        int4 sv = *(const int4*)(ei + i);
        int4 dv = *(const int4*)(ei + E + i);
        int pos;
        pos = atomicAdd(&cur[dv.x >> BSHIFT], 1);
        sbuf[pos] = (unsigned)sv.x | ((unsigned)(dv.x & BMASK) << 17);
        pos = atomicAdd(&cur[dv.y >> BSHIFT], 1);
        sbuf[pos] = (unsigned)sv.y | ((unsigned)(dv.y & BMASK) << 17);
        pos = atomicAdd(&cur[dv.z >> BSHIFT], 1);
        sbuf[pos] = (unsigned)sv.z | ((unsigned)(dv.z & BMASK) << 17);
        pos = atomicAdd(&cur[dv.w >> BSHIFT], 1);
        sbuf[pos] = (unsigned)sv.w | ((unsigned)(dv.w & BMASK) << 17);
    }
}

// ================= per-bucket counting sort -> CSR =================
// One 512-thread block per 128-node bucket: stage records into LDS, hist,
// two-wave shfl scan -> rowptr, LDS->LDS counting sort, COALESCED ssrc
// writeback. No gather work here — R18 showed fusing the gather into this
// block serializes it behind the sort phases. Keep blocks short.
__global__ __launch_bounds__(512) void k_sort(
        const unsigned* __restrict__ sbuf, const int* __restrict__ table,
        int* __restrict__ rowptr, int* __restrict__ ssrc,
        int N, int E, int NBUCK) {
    __shared__ int hist[128];
    __shared__ int sc[128];
    __shared__ int cur[128];
    __shared__ unsigned raws[CAP];
    __shared__ int sls[CAP];
    int b = blockIdx.x;
    int t = threadIdx.x;
    int lo = table[b * SLICES];
    int hi = (b + 1 < NBUCK) ? table[(b + 1) * SLICES] : E;
    int cnt = hi - lo;
    bool inLds = (cnt <= CAP);

    if (t < 128) hist[t] = 0;
    __syncthreads();

    if (inLds) {
        for (int i = t; i < cnt; i += 512) {
            unsigned v = sbuf[lo + i];
            raws[i] = v;
            atomicAdd(&hist[v >> 17], 1);
        }
    } else {
        for (int i = lo + t; i < hi; i += 512) atomicAdd(&hist[sbuf[i] >> 17], 1);
    }
    __syncthreads();

    if (t < 128) {  // two-wave shfl inclusive scan of 128 bins
        int lane = t & 63;
        int own = hist[t];
        int v = own;
#pragma unroll
        for (int off = 1; off < 64; off <<= 1) {
            int u = __shfl_up(v, off);
            if (lane >= off) v += u;
        }
        sc[t] = v;
    }
    __syncthreads();
    if (t < 128) {
        int ex = sc[t] - hist[t] + (t >= 64 ? sc[63] : 0);
        cur[t] = ex;
        int node = (b << BSHIFT) + t;
        if (node < N) rowptr[node] = lo + ex;
    }
    __syncthreads();

    if (inLds) {
        for (int i = t; i < cnt; i += 512) {
            unsigned v = raws[i];
            int pos = atomicAdd(&cur[v >> 17], 1);
            sls[pos] = (int)(v & SRCMASK);
        }
        __syncthreads();
        for (int i = t; i < cnt; i += 512) ssrc[lo + i] = sls[i];  // coalesced
    } else {  // overflow fallback (statistically never: mean 2048, CAP 2816)
        for (int i = lo + t; i < hi; i += 512) {
            unsigned v = sbuf[i];
            int pos = atomicAdd(&cur[v >> 17], 1);
            ssrc[lo + pos] = (int)(v & SRCMASK);
        }
    }
}

// ================= layer 1 gather + transform 2 (node-parallel) =================
// R1 restructure: 4 lanes/node, 4-edge batches. R0 showed gather1 is bound by
// exposed latency with ~1 outstanding load/wave (de-indirecting x didn't help:
// 48->44us, still 24% VALU / 2.3% HBM). Fix: each lane issues 4 independent
// ssrc loads then 4 independent x gathers (8 in flight), wave count halves.
// x is 800KB = cache-hot; the latency being hidden is the ssrc stream.
// Straight-line softmax (no max): inputs N(0,1)-scale, |e|<~8 — validated
// R8-R18. Epilogue folds W1->relu->W2 (lane q does heads q and q+4).
__global__ __launch_bounds__(256) void k_gather1(
        const int* __restrict__ rowptr, const int* __restrict__ ssrc,
        const float* __restrict__ x,
        const float* __restrict__ W1, const float* __restrict__ att_src1,
        const float* __restrict__ att_dst1, const float* __restrict__ b1,
        const float* __restrict__ W2, float* __restrict__ h2, int N) {
    __shared__ float pbuf[32];  // Ps d0 | Ps d1 | Pd d0 | Pd d1 (8 heads each)
    int t = threadIdx.x;
    if (t < 32) {  // rank-2 projections
        int which = t >> 4;   // 0=src, 1=dst
        int hd = t & 15;
        int h = hd >> 1, d = hd & 1;
        const float* att = which ? att_dst1 : att_src1;
        float s = 0.0f;
#pragma unroll
        for (int c = 0; c < 16; ++c) s += W1[d * 128 + h * 16 + c] * att[h * 16 + c];
        pbuf[which * 16 + d * 8 + h] = s;
    }
    __syncthreads();

    int idx = blockIdx.x * blockDim.x + t;
    int n = idx >> 2, q = idx & 3;
    if (n >= N) return;
    const float2* x2 = (const float2*)x;
    int start = rowptr[n], end = rowptr[n + 1];
    float2 xn = x2[n];
    float Ps0[8], Ps1[8], adv[8], l[8], s0[8], s1[8];
#pragma unroll
    for (int h = 0; h < 8; ++h) {
        Ps0[h] = pbuf[h];
        Ps1[h] = pbuf[8 + h];
        adv[h] = xn.x * pbuf[16 + h] + xn.y * pbuf[24 + h];
        l[h] = 0.f; s0[h] = 0.f; s1[h] = 0.f;
    }
    // 4-edge batch per lane per round: 4 independent ssrc loads, then 4
    // independent x gathers. Clamp OOB lanes to edge j (mask kills their p).
    for (int j = start + q * 4; j < end; j += 16) {
        int rem = end - j;  // >= 1
        int i1 = j + (rem > 1 ? 1 : 0);
        int i2 = j + (rem > 2 ? 2 : 0);
        int i3 = j + (rem > 3 ? 3 : 0);
        int sa = ssrc[j], sb = ssrc[i1], sc = ssrc[i2], sd = ssrc[i3];
        float2 xa = x2[sa], xb = x2[sb], xc = x2[sc], xd = x2[sd];
        float m1 = rem > 1 ? 1.f : 0.f;
        float m2 = rem > 2 ? 1.f : 0.f;
        float m3 = rem > 3 ? 1.f : 0.f;
#pragma unroll
        for (int h = 0; h < 8; ++h) {
            float pa = __expf(leaky(xa.x * Ps0[h] + xa.y * Ps1[h] + adv[h]));
            float pb = __expf(leaky(xb.x * Ps0[h] + xb.y * Ps1[h] + adv[h])) * m1;
            float pc = __expf(leaky(xc.x * Ps0[h] + xc.y * Ps1[h] + adv[h])) * m2;
            float pd = __expf(leaky(xd.x * Ps0[h] + xd.y * Ps1[h] + adv[h])) * m3;
            l[h] += (pa + pb) + (pc + pd);
            s0[h] += (pa * xa.x + pb * xb.x) + (pc * xc.x + pd * xd.x);
            s1[h] += (pa * xa.y + pb * xb.y) + (pc * xc.y + pd * xd.y);
        }
    }
#pragma unroll
    for (int off = 1; off < 4; off <<= 1) {
#pragma unroll
        for (int h = 0; h < 8; ++h) {
            l[h] += __shfl_xor(l[h], off);
            s0[h] += __shfl_xor(s0[h], off);
            s1[h] += __shfl_xor(s1[h], off);
        }
    }
    // lane q folds heads q and q+4 through W1->relu->W2
    float h0 = 0.f, h1v = 0.f, h2v = 0.f, h3 = 0.f;
#pragma unroll
    for (int hh = 0; hh < 2; ++hh) {
        int head = q + hh * 4;
        float inv = 1.0f / (l[head] + kEps);
        float sX0 = s0[head] * inv, sX1 = s1[head] * inv;
#pragma unroll
        for (int c = 0; c < 16; ++c) {
            int col = head * 16 + c;
            float o = fmaxf(W1[col] * sX0 + W1[128 + col] * sX1 + b1[col], 0.0f);
            h0 += o * W2[col * 4 + 0];
            h1v += o * W2[col * 4 + 1];
            h2v += o * W2[col * 4 + 2];
            h3 += o * W2[col * 4 + 3];
        }
    }
#pragma unroll
    for (int off = 1; off < 4; off <<= 1) {
        h0 += __shfl_xor(h0, off);
        h1v += __shfl_xor(h1v, off);
        h2v += __shfl_xor(h2v, off);
        h3 += __shfl_xor(h3, off);
    }
    if (q == 0) {
        ((float4*)h2)[n] = make_float4(h0, h1v, h2v, h3);
    }
}

// ================= layer 2 gather + log_softmax =================
// 4 lanes/node, 4-edge batches (same MLP restructure as k_gather1): 4
// independent ssrc loads -> 4 independent 16B h2 gathers in flight. h2 is
// 1.6MB (L2-resident); the latency being hidden is the ssrc stream + L2.
__global__ __launch_bounds__(256) void k_gather2_out(
        const int* __restrict__ rowptr, const int* __restrict__ ssrc,
        const float* __restrict__ h2, const float* __restrict__ att_src2,
        const float* __restrict__ att_dst2, const float* __restrict__ b2,
        float* __restrict__ out, int N) {
    int idx = blockIdx.x * blockDim.x + threadIdx.x;
    int n = idx >> 2, q = idx & 3;
    if (n >= N) return;
    int start = rowptr[n], end = rowptr[n + 1];
    float4 as2 = *(const float4*)att_src2;
    float4 ad2v = *(const float4*)att_dst2;
    const float4* h4 = (const float4*)h2;
    float4 hn = h4[n];
    float ad = hn.x * ad2v.x + hn.y * ad2v.y + hn.z * ad2v.z + hn.w * ad2v.w;
    float l = 0.0f;
    float4 acc = make_float4(0.f, 0.f, 0.f, 0.f);
    for (int j = start + q * 4; j < end; j += 16) {
        int rem = end - j;  // >= 1
        int i1 = j + (rem > 1 ? 1 : 0);
        int i2 = j + (rem > 2 ? 2 : 0);
        int i3 = j + (rem > 3 ? 3 : 0);
        int sa = ssrc[j], sb = ssrc[i1], sc = ssrc[i2], sd = ssrc[i3];
        float4 ha = h4[sa], hb = h4[sb], hc = h4[sc], hd = h4[sd];
        float m1 = rem > 1 ? 1.f : 0.f;
        float m2 = rem > 2 ? 1.f : 0.f;
        float m3 = rem > 3 ? 1.f : 0.f;
        float p0 = __expf(leaky(ha.x * as2.x + ha.y * as2.y + ha.z * as2.z + ha.w * as2.w + ad));
        float p1 = __expf(leaky(hb.x * as2.x + hb.y * as2.y + hb.z * as2.z + hb.w * as2.w + ad)) * m1;
        float p2 = __expf(leaky(hc.x * as2.x + hc.y * as2.y + hc.z * as2.z + hc.w * as2.w + ad)) * m2;
        float p3 = __expf(leaky(hd.x * as2.x + hd.y * as2.y + hd.z * as2.z + hd.w * as2.w + ad)) * m3;
        l += (p0 + p1) + (p2 + p3);
        acc.x += (p0 * ha.x + p1 * hb.x) + (p2 * hc.x + p3 * hd.x);
        acc.y += (p0 * ha.y + p1 * hb.y) + (p2 * hc.y + p3 * hd.y);
        acc.z += (p0 * ha.z + p1 * hb.z) + (p2 * hc.z + p3 * hd.z);
        acc.w += (p0 * ha.w + p1 * hb.w) + (p2 * hc.w + p3 * hd.w);
    }
#pragma unroll
    for (int off = 1; off < 4; off <<= 1) {
        l += __shfl_xor(l, off);
        acc.x += __shfl_xor(acc.x, off);
        acc.y += __shfl_xor(acc.y, off);
        acc.z += __shfl_xor(acc.z, off);
        acc.w += __shfl_xor(acc.w, off);
    }
    if (q == 0) {
        float inv = 1.0f / (l + kEps);
        float4 v = make_float4(acc.x * inv + b2[0], acc.y * inv + b2[1],
                               acc.z * inv + b2[2], acc.w * inv + b2[3]);
        float mx = fmaxf(fmaxf(v.x, v.y), fmaxf(v.z, v.w));
        float sum = __expf(v.x - mx) + __expf(v.y - mx) + __expf(v.z - mx) + __expf(v.w - mx);
        float lse = mx + logf(sum);
        ((float4*)out)[n] = make_float4(v.x - lse, v.y - lse, v.z - lse, v.w - lse);
    }
}

extern "C" void kernel_launch(void* const* d_in, const int* in_sizes, int n_in,
                              void* d_out, int out_size, void* d_ws, size_t ws_size,
                              hipStream_t stream) {
    const float* x        = (const float*)d_in[0];
    const int*   ei       = (const int*)d_in[1];
    const float* W1       = (const float*)d_in[2];
    const float* att_src1 = (const float*)d_in[3];
    const float* att_dst1 = (const float*)d_in[4];
    const float* b1       = (const float*)d_in[5];
    const float* W2       = (const float*)d_in[6];
    const float* att_src2 = (const float*)d_in[7];
    const float* att_dst2 = (const float*)d_in[8];
    const float* b2       = (const float*)d_in[9];

    const int N = in_sizes[0] / 2;           // x is [N,2]
    const int E = in_sizes[1] / 2;           // edge_index is [2,E]
    const int NBUCK = (N + BMASK) >> BSHIFT; // 128-node buckets (<= 832)
    const int ntable = NBUCK * SLICES;
    const int nsb = (ntable + 1023) / 1024;  // scan chunks

    // ---- workspace layout (4B elems) ----
    int* table     = (int*)d_ws;                  // ntable (+64 pad)
    int* partial   = table + ntable + 64;         // nsb (pad 1024)
    int* rowptr    = partial + 1024;              // N+1 -> pad N+4
    int* ssrc      = rowptr + ((N + 4) & ~3);     // E
    unsigned* sbuf = (unsigned*)(ssrc + E);       // E
    float* h2      = (float*)(sbuf + E);          // N*4

    // bucketed partition (by destination), no global atomics
    k_hist1<<<SLICES, 512, 0, stream>>>(ei, table, rowptr, E, N, NBUCK);
    k_scan_reduce<<<nsb, 256, 0, stream>>>(table, partial, ntable);
    k_scan_apply<<<nsb, 256, 0, stream>>>(table, partial, ntable, nsb);
    k_bin2<<<SLICES, 512, 0, stream>>>(ei, table, sbuf, E, NBUCK);

    // per-bucket counting sort -> CSR
    k_sort<<<NBUCK, 512, 0, stream>>>(sbuf, table, rowptr, ssrc, N, E, NBUCK);

    // layer 1 gather + transform 2 (node-parallel, 4 lanes/node)
    k_gather1<<<(N * 4 + 255) / 256, 256, 0, stream>>>(rowptr, ssrc, x,
                                                       W1, att_src1, att_dst1, b1,
                                                       W2, h2, N);

    // layer 2 gather + log_softmax (4 lanes/node)
    k_gather2_out<<<(N * 4 + 255) / 256, 256, 0, stream>>>(rowptr, ssrc, h2,
                                                           att_src2, att_dst2, b2,
                                                           (float*)d_out, N);
}

// Round 3
// 151.197 us; speedup vs baseline: 1.1421x; 1.1164x over previous
//
#include <hip/hip_runtime.h>
#include <math.h>

static constexpr float kNegSlope = 0.2f;
static constexpr float kEps = 1e-16f;
static constexpr int SLICES = 256;   // partition slices for hist/bin passes
static constexpr int BSHIFT = 7;     // 128 nodes per bucket
static constexpr int BMASK = 127;
static constexpr unsigned SRCMASK = 0x1FFFFu;  // 17 bits (N < 131072)
static constexpr int CAP = 2816;     // LDS bucket capacity (mean 2048, +17 sigma)

__device__ __forceinline__ float leaky(float v) {
    return v > 0.0f ? v : kNegSlope * v;
}

// ================= atomic-free bucketed partition =================
// bucket = dst >> 7 (128 nodes). Per-slice private LDS histograms ->
// scan of table[bucket][slice] -> deterministic scatter with LDS cursors.
// Record: src | (d&127)<<17 (24 bits). 4B records ONLY — R16 showed widening
// the scattered record (8B) doubles write amplification. No global atomics.

__global__ __launch_bounds__(512) void k_hist1(const int* __restrict__ ei,
                                               int* __restrict__ table,
                                               int* __restrict__ rowptr,
                                               int E, int N, int NBUCK) {
    __shared__ int hist[832];
    int b = blockIdx.x, t = threadIdx.x;
    if (b == 0 && t == 0) rowptr[N] = E;  // sentinel
    for (int i = t; i < NBUCK; i += 512) hist[i] = 0;
    __syncthreads();
    int S = (((E + SLICES - 1) / SLICES) + 3) & ~3;  // slice size, multiple of 4
    int lo = b * S, hi = min(lo + S, E);
    for (int i = lo + t * 4; i < hi; i += 512 * 4) {
        int4 dv = *(const int4*)(ei + E + i);
        atomicAdd(&hist[dv.x >> BSHIFT], 1);
        atomicAdd(&hist[dv.y >> BSHIFT], 1);
        atomicAdd(&hist[dv.z >> BSHIFT], 1);
        atomicAdd(&hist[dv.w >> BSHIFT], 1);
    }
    __syncthreads();
    for (int i = t; i < NBUCK; i += 512) table[i * SLICES + b] = hist[i];
}

// Scan pass 1: block b sums its 1024-int chunk -> partial[b].
__global__ __launch_bounds__(256) void k_scan_reduce(const int* __restrict__ src,
                                                     int* __restrict__ partial, int n) {
    __shared__ int wsum[4];
    int b = blockIdx.x, t = threadIdx.x;
    int base = b * 1024 + t * 4;
    int s = 0;
#pragma unroll
    for (int k = 0; k < 4; ++k) {
        int idx = base + k;
        s += (idx < n) ? src[idx] : 0;
    }
#pragma unroll
    for (int off = 1; off < 64; off <<= 1) s += __shfl_xor(s, off);
    if ((t & 63) == 0) wsum[t >> 6] = s;
    __syncthreads();
    if (t == 0) partial[b] = wsum[0] + wsum[1] + wsum[2] + wsum[3];
}

// Scan pass 2: block b computes its chunk base by reducing partial[i<b],
// then wave-scans its 1024-int chunk in place (exclusive).
__global__ __launch_bounds__(256) void k_scan_apply(int* __restrict__ data,
                                                    const int* __restrict__ partial,
                                                    int n, int nsb) {
    __shared__ int sm[8];
    __shared__ int baseSh;
    int b = blockIdx.x, t = threadIdx.x;
    int acc = 0;
    for (int i = t; i < b; i += 256) acc += partial[i];
#pragma unroll
    for (int off = 1; off < 64; off <<= 1) acc += __shfl_xor(acc, off);
    if ((t & 63) == 0) sm[t >> 6] = acc;
    __syncthreads();
    if (t == 0) baseSh = sm[0] + sm[1] + sm[2] + sm[3];
    __syncthreads();
    int chunkBase = baseSh;
    __syncthreads();  // sm reused below
    int base = b * 1024 + t * 4;
    int v[4];
#pragma unroll
    for (int k = 0; k < 4; ++k) {
        int idx = base + k;
        v[k] = (idx < n) ? data[idx] : 0;
    }
    int sum4 = v[0] + v[1] + v[2] + v[3];
    int s = sum4;
#pragma unroll
    for (int off = 1; off < 64; off <<= 1) {
        int u = __shfl_up(s, off);
        if ((t & 63) >= off) s += u;
    }
    if ((t & 63) == 63) sm[t >> 6] = s;
    __syncthreads();
    int woff = 0;
    int w = t >> 6;
    for (int ww = 0; ww < w; ++ww) woff += sm[ww];
    int ex = chunkBase + woff + (s - sum4);
#pragma unroll
    for (int k = 0; k < 4; ++k) {
        int idx = base + k;
        if (idx < n) data[idx] = ex;
        ex += v[k];
    }
}

__global__ __launch_bounds__(512) void k_bin2(const int* __restrict__ ei,
                                              const int* __restrict__ table,
                                              unsigned* __restrict__ sbuf, int E, int NBUCK) {
    __shared__ int cur[832];
    int b = blockIdx.x, t = threadIdx.x;
    for (int i = t; i < NBUCK; i += 512) cur[i] = table[i * SLICES + b];
    __syncthreads();
    int S = (((E + SLICES - 1) / SLICES) + 3) & ~3;
    int lo = b * S, hi = min(lo + S, E);
    for (int i = lo + t * 4; i < hi; i += 512 * 4) {
        int4 sv = *(const int4*)(ei + i);
        int4 dv = *(const int4*)(ei + E + i);
        int pos;
        pos = atomicAdd(&cur[dv.x >> BSHIFT], 1);
        sbuf[pos] = (unsigned)sv.x | ((unsigned)(dv.x & BMASK) << 17);
        pos = atomicAdd(&cur[dv.y >> BSHIFT], 1);
        sbuf[pos] = (unsigned)sv.y | ((unsigned)(dv.y & BMASK) << 17);
        pos = atomicAdd(&cur[dv.z >> BSHIFT], 1);
        sbuf[pos] = (unsigned)sv.z | ((unsigned)(dv.z & BMASK) << 17);
        pos = atomicAdd(&cur[dv.w >> BSHIFT], 1);
        sbuf[pos] = (unsigned)sv.w | ((unsigned)(dv.w & BMASK) << 17);
    }
}

// ================= per-bucket counting sort -> CSR =================
// One 512-thread block per 128-node bucket: stage records into LDS, hist,
// two-wave shfl scan -> rowptr, LDS->LDS counting sort, COALESCED ssrc
// writeback. No gather work here — R18 showed fusing the gather into this
// block serializes it behind the sort phases. Keep blocks short.
__global__ __launch_bounds__(512) void k_sort(
        const unsigned* __restrict__ sbuf, const int* __restrict__ table,
        int* __restrict__ rowptr, int* __restrict__ ssrc,
        int N, int E, int NBUCK) {
    __shared__ int hist[128];
    __shared__ int sc[128];
    __shared__ int cur[128];
    __shared__ unsigned raws[CAP];
    __shared__ int sls[CAP];
    int b = blockIdx.x;
    int t = threadIdx.x;
    int lo = table[b * SLICES];
    int hi = (b + 1 < NBUCK) ? table[(b + 1) * SLICES] : E;
    int cnt = hi - lo;
    bool inLds = (cnt <= CAP);

    if (t < 128) hist[t] = 0;
    __syncthreads();

    if (inLds) {
        for (int i = t; i < cnt; i += 512) {
            unsigned v = sbuf[lo + i];
            raws[i] = v;
            atomicAdd(&hist[v >> 17], 1);
        }
    } else {
        for (int i = lo + t; i < hi; i += 512) atomicAdd(&hist[sbuf[i] >> 17], 1);
    }
    __syncthreads();

    if (t < 128) {  // two-wave shfl inclusive scan of 128 bins
        int lane = t & 63;
        int own = hist[t];
        int v = own;
#pragma unroll
        for (int off = 1; off < 64; off <<= 1) {
            int u = __shfl_up(v, off);
            if (lane >= off) v += u;
        }
        sc[t] = v;
    }
    __syncthreads();
    if (t < 128) {
        int ex = sc[t] - hist[t] + (t >= 64 ? sc[63] : 0);
        cur[t] = ex;
        int node = (b << BSHIFT) + t;
        if (node < N) rowptr[node] = lo + ex;
    }
    __syncthreads();

    if (inLds) {
        for (int i = t; i < cnt; i += 512) {
            unsigned v = raws[i];
            int pos = atomicAdd(&cur[v >> 17], 1);
            sls[pos] = (int)(v & SRCMASK);
        }
        __syncthreads();
        for (int i = t; i < cnt; i += 512) ssrc[lo + i] = sls[i];  // coalesced
    } else {  // overflow fallback (statistically never: mean 2048, CAP 2816)
        for (int i = lo + t; i < hi; i += 512) {
            unsigned v = sbuf[i];
            int pos = atomicAdd(&cur[v >> 17], 1);
            ssrc[lo + pos] = (int)(v & SRCMASK);
        }
    }
}

// ================= layer 1 attention accumulate (node-parallel) =================
// R2 restructure: R0/R1 showed gather1 is INSENSITIVE to memory structure
// (stream 44us / dep-gather 48us / 8-wide MLP 49us) -> not memory-bound.
// Static count: the per-lane W1->relu->W2 epilogue (112 VMEM + ~180 VALU +
// swizzle chains) was >= half of all issued instructions. Remove it: this
// kernel ends at the softmax reduce and emits normalized (sX0,sX1) per
// (node,head) in two coalesced planes; k_fold does the dense MLP.
// 8 lanes/node, unroll-2 edge loop, direct x gather (R0: gather == stream).
// Straight-line softmax (no max): inputs N(0,1)-scale, |e|<~8 — validated
// R8-R18.
__global__ __launch_bounds__(256) void k_gather1(
        const int* __restrict__ rowptr, const int* __restrict__ ssrc,
        const float* __restrict__ x,
        const float* __restrict__ W1, const float* __restrict__ att_src1,
        const float* __restrict__ att_dst1,
        float* __restrict__ attA, float* __restrict__ attB, int N) {
    __shared__ float pbuf[32];  // Ps d0 | Ps d1 | Pd d0 | Pd d1 (8 heads each)
    int t = threadIdx.x;
    if (t < 32) {  // rank-2 projections
        int which = t >> 4;   // 0=src, 1=dst
        int hd = t & 15;
        int h = hd >> 1, d = hd & 1;
        const float* att = which ? att_dst1 : att_src1;
        float s = 0.0f;
#pragma unroll
        for (int c = 0; c < 16; ++c) s += W1[d * 128 + h * 16 + c] * att[h * 16 + c];
        pbuf[which * 16 + d * 8 + h] = s;
    }
    __syncthreads();

    int idx = blockIdx.x * blockDim.x + t;
    int n = idx >> 3, q = idx & 7;
    if (n >= N) return;
    const float2* x2 = (const float2*)x;
    int start = rowptr[n], end = rowptr[n + 1];
    float2 xn = x2[n];
    float Ps0[8], Ps1[8], adv[8], l[8], s0[8], s1[8];
#pragma unroll
    for (int h = 0; h < 8; ++h) {
        Ps0[h] = pbuf[h];
        Ps1[h] = pbuf[8 + h];
        adv[h] = xn.x * pbuf[16 + h] + xn.y * pbuf[24 + h];
        l[h] = 0.f; s0[h] = 0.f; s1[h] = 0.f;
    }
    int j = start + q;
    for (; j + 8 < end; j += 16) {  // unroll-2: two independent gathers
        int sa = ssrc[j];
        int sb = ssrc[j + 8];
        float2 xa = x2[sa];
        float2 xb = x2[sb];
#pragma unroll
        for (int h = 0; h < 8; ++h) {
            float pa = __expf(leaky(xa.x * Ps0[h] + xa.y * Ps1[h] + adv[h]));
            float pb = __expf(leaky(xb.x * Ps0[h] + xb.y * Ps1[h] + adv[h]));
            l[h] += pa + pb;
            s0[h] += pa * xa.x + pb * xb.x;
            s1[h] += pa * xa.y + pb * xb.y;
        }
    }
    if (j < end) {  // at most one tail edge per lane
        int sa = ssrc[j];
        float2 xa = x2[sa];
#pragma unroll
        for (int h = 0; h < 8; ++h) {
            float pa = __expf(leaky(xa.x * Ps0[h] + xa.y * Ps1[h] + adv[h]));
            l[h] += pa;
            s0[h] += pa * xa.x;
            s1[h] += pa * xa.y;
        }
    }
#pragma unroll
    for (int off = 1; off < 8; off <<= 1) {
#pragma unroll
        for (int h = 0; h < 8; ++h) {
            l[h] += __shfl_xor(l[h], off);
            s0[h] += __shfl_xor(s0[h], off);
            s1[h] += __shfl_xor(s1[h], off);
        }
    }
    // lane q emits head q's normalized feature pair (planar, coalesced:
    // wave writes 64 consecutive floats per plane)
    float inv = 1.0f / (l[q] + kEps);
    attA[n * 8 + q] = s0[q] * inv;
    attB[n * 8 + q] = s1[q] * inv;
}

// ================= dense per-node MLP: W1 -> relu -> W2 =================
// 1 thread/node. Weights packed into two float4 LDS tables (uniform-address
// broadcast reads, conflict-free). h2[n] = sum over all 128 concat cols of
// relu(W1a[c]*sX0[h] + W1b[c]*sX1[h] + b1[c]) * W2[c][:], h = c>>4.
__global__ __launch_bounds__(256) void k_fold(
        const float* __restrict__ attA, const float* __restrict__ attB,
        const float* __restrict__ W1, const float* __restrict__ b1,
        const float* __restrict__ W2, float* __restrict__ h2, int N) {
    __shared__ float4 pk1[128];  // (W1a, W1b, b1, 0) per col
    __shared__ float4 pk2[128];  // W2 row per col
    int t = threadIdx.x;
    if (t < 128) {
        pk1[t] = make_float4(W1[t], W1[128 + t], b1[t], 0.f);
        pk2[t] = ((const float4*)W2)[t];
    }
    __syncthreads();
    int n = blockIdx.x * 256 + t;
    if (n >= N) return;
    const float4* A = (const float4*)(attA + n * 8);
    const float4* B = (const float4*)(attB + n * 8);
    float4 a01 = A[0], a23 = A[1];
    float4 b01 = B[0], b23 = B[1];
    float4 acc = make_float4(0.f, 0.f, 0.f, 0.f);
#pragma unroll
    for (int h = 0; h < 8; ++h) {  // ternaries fold at compile time
        float sx0 = (h == 0) ? a01.x : (h == 1) ? a01.y : (h == 2) ? a01.z :
                    (h == 3) ? a01.w : (h == 4) ? a23.x : (h == 5) ? a23.y :
                    (h == 6) ? a23.z : a23.w;
        float sx1 = (h == 0) ? b01.x : (h == 1) ? b01.y : (h == 2) ? b01.z :
                    (h == 3) ? b01.w : (h == 4) ? b23.x : (h == 5) ? b23.y :
                    (h == 6) ? b23.z : b23.w;
#pragma unroll
        for (int c = 0; c < 16; ++c) {
            int col = h * 16 + c;
            float4 p = pk1[col];
            float o = fmaxf(p.x * sx0 + p.y * sx1 + p.z, 0.0f);
            float4 w = pk2[col];
            acc.x += o * w.x;
            acc.y += o * w.y;
            acc.z += o * w.z;
            acc.w += o * w.w;
        }
    }
    ((float4*)h2)[n] = acc;
}

// ================= layer 2 gather + log_softmax =================
// 8 lanes/node; unroll-2 keeps two independent ssrc->h2 chains in flight.
// (R1's 4-lane masked variant attributed ~+4us — reverted to this form.)
__global__ __launch_bounds__(256) void k_gather2_out(
        const int* __restrict__ rowptr, const int* __restrict__ ssrc,
        const float* __restrict__ h2, const float* __restrict__ att_src2,
        const float* __restrict__ att_dst2, const float* __restrict__ b2,
        float* __restrict__ out, int N) {
    int idx = blockIdx.x * blockDim.x + threadIdx.x;
    int n = idx >> 3, q = idx & 7;
    if (n >= N) return;
    int start = rowptr[n], end = rowptr[n + 1];
    float4 as2 = *(const float4*)att_src2;
    float4 ad2v = *(const float4*)att_dst2;
    const float4* h4 = (const float4*)h2;
    float4 hn = h4[n];
    float ad = hn.x * ad2v.x + hn.y * ad2v.y + hn.z * ad2v.z + hn.w * ad2v.w;
    float l = 0.0f;
    float4 acc = make_float4(0.f, 0.f, 0.f, 0.f);
    int j = start + q;
    for (; j + 8 < end; j += 16) {  // two independent gathers in flight
        int s0 = ssrc[j];
        int s1 = ssrc[j + 8];
        float4 ha = h4[s0];
        float4 hb = h4[s1];
        float e0 = ha.x * as2.x + ha.y * as2.y + ha.z * as2.z + ha.w * as2.w + ad;
        float e1 = hb.x * as2.x + hb.y * as2.y + hb.z * as2.z + hb.w * as2.w + ad;
        float p0 = __expf(leaky(e0));
        float p1 = __expf(leaky(e1));
        l += p0 + p1;
        acc.x += p0 * ha.x + p1 * hb.x;
        acc.y += p0 * ha.y + p1 * hb.y;
        acc.z += p0 * ha.z + p1 * hb.z;
        acc.w += p0 * ha.w + p1 * hb.w;
    }
    if (j < end) {  // at most one tail edge per lane
        int s0 = ssrc[j];
        float4 ha = h4[s0];
        float e0 = ha.x * as2.x + ha.y * as2.y + ha.z * as2.z + ha.w * as2.w + ad;
        float p0 = __expf(leaky(e0));
        l += p0;
        acc.x += p0 * ha.x;
        acc.y += p0 * ha.y;
        acc.z += p0 * ha.z;
        acc.w += p0 * ha.w;
    }
#pragma unroll
    for (int off = 1; off < 8; off <<= 1) {
        l += __shfl_xor(l, off);
        acc.x += __shfl_xor(acc.x, off);
        acc.y += __shfl_xor(acc.y, off);
        acc.z += __shfl_xor(acc.z, off);
        acc.w += __shfl_xor(acc.w, off);
    }
    if (q == 0) {
        float inv = 1.0f / (l + kEps);
        float4 v = make_float4(acc.x * inv + b2[0], acc.y * inv + b2[1],
                               acc.z * inv + b2[2], acc.w * inv + b2[3]);
        float mx = fmaxf(fmaxf(v.x, v.y), fmaxf(v.z, v.w));
        float sum = __expf(v.x - mx) + __expf(v.y - mx) + __expf(v.z - mx) + __expf(v.w - mx);
        float lse = mx + logf(sum);
        ((float4*)out)[n] = make_float4(v.x - lse, v.y - lse, v.z - lse, v.w - lse);
    }
}

extern "C" void kernel_launch(void* const* d_in, const int* in_sizes, int n_in,
                              void* d_out, int out_size, void* d_ws, size_t ws_size,
                              hipStream_t stream) {
    const float* x        = (const float*)d_in[0];
    const int*   ei       = (const int*)d_in[1];
    const float* W1       = (const float*)d_in[2];
    const float* att_src1 = (const float*)d_in[3];
    const float* att_dst1 = (const float*)d_in[4];
    const float* b1       = (const float*)d_in[5];
    const float* W2       = (const float*)d_in[6];
    const float* att_src2 = (const float*)d_in[7];
    const float* att_dst2 = (const float*)d_in[8];
    const float* b2       = (const float*)d_in[9];

    const int N = in_sizes[0] / 2;           // x is [N,2]
    const int E = in_sizes[1] / 2;           // edge_index is [2,E]
    const int NBUCK = (N + BMASK) >> BSHIFT; // 128-node buckets (<= 832)
    const int ntable = NBUCK * SLICES;
    const int nsb = (ntable + 1023) / 1024;  // scan chunks

    // ---- workspace layout (4B elems) ----
    // attA/attB (N*16 floats) OVERLAY sbuf (dead after k_sort); h2 follows
    // whichever of {sbuf, att} extends further. Net footprint <= R0's proven.
    int* table     = (int*)d_ws;                  // ntable (+64 pad)
    int* partial   = table + ntable + 64;         // nsb (pad 1024)
    int* rowptr    = partial + 1024;              // N+1 -> pad N+4
    int* ssrc      = rowptr + ((N + 4) & ~3);     // E
    unsigned* sbuf = (unsigned*)(ssrc + E);       // E (dead after k_sort)
    float* attA    = (float*)sbuf;                // N*8 floats (overlay)
    float* attB    = attA + (size_t)N * 8;        // N*8 floats
    size_t post    = (size_t)E > (size_t)N * 16 ? (size_t)E : (size_t)N * 16;
    float* h2      = (float*)(sbuf + post);       // N*4 floats

    // bucketed partition (by destination), no global atomics
    k_hist1<<<SLICES, 512, 0, stream>>>(ei, table, rowptr, E, N, NBUCK);
    k_scan_reduce<<<nsb, 256, 0, stream>>>(table, partial, ntable);
    k_scan_apply<<<nsb, 256, 0, stream>>>(table, partial, ntable, nsb);
    k_bin2<<<SLICES, 512, 0, stream>>>(ei, table, sbuf, E, NBUCK);

    // per-bucket counting sort -> CSR
    k_sort<<<NBUCK, 512, 0, stream>>>(sbuf, table, rowptr, ssrc, N, E, NBUCK);

    // layer 1: attention accumulate (lean) -> dense MLP fold
    k_gather1<<<(N * 8 + 255) / 256, 256, 0, stream>>>(rowptr, ssrc, x,
                                                       W1, att_src1, att_dst1,
                                                       attA, attB, N);
    k_fold<<<(N + 255) / 256, 256, 0, stream>>>(attA, attB, W1, b1, W2, h2, N);

    // layer 2 gather + log_softmax
    k_gather2_out<<<(N * 8 + 255) / 256, 256, 0, stream>>>(rowptr, ssrc, h2,
                                                           att_src2, att_dst2, b2,
                                                           (float*)d_out, N);
}